// Round 2
// baseline (454.304 us; speedup 1.0000x reference)
//
#include <hip/hip_runtime.h>
#include <cstdint>

// Problem constants
#define TOKENS 8192
#define DIM 4096
#define D4 (DIM / 4)            // 1024 float4 per row
#define NEXP 8
#define TOPK 2
#define SLOTS (TOKENS * TOPK)   // 16384

// Routing-kernel geometry
#define NBLK 512                // 2 blocks/CU on 256 CUs -> all co-resident
#define TPB 256                 // 4 waves
#define CH 32                   // slots per block == chunk size

// Output layout (all fp32, concatenated in reference return order)
#define OUT_CNT ((size_t)SLOTS * DIM)       // 67108864
#define OUT_SCAT (OUT_CNT + NEXP)           // 67108872
#define OUT_SCORE (OUT_SCAT + SLOTS)        // 67125256

typedef float vfloat4 __attribute__((ext_vector_type(4)));

// ---------------------------------------------------------------------------
// Kernel 1: fused routing. score -> (grid bar) -> scan by block 0 ->
// (grid bar) -> rank + emit dstpos/scatter_indices/scores_sorted/counts.
// All metadata stays on-chip except the 512x8 hist and the final outputs.
// ---------------------------------------------------------------------------
__global__ __launch_bounds__(TPB, 2) void k_route(const float* __restrict__ x,
                                                  const float* __restrict__ W,
                                                  int* __restrict__ hist,
                                                  int* __restrict__ bar,
                                                  int* __restrict__ dstpos,
                                                  float* __restrict__ out)
{
    __shared__ int   s_eid[CH];
    __shared__ float s_prob[CH];
    __shared__ int   s_cnt[NEXP];

    const int wave = threadIdx.x >> 6;
    const int lane = threadIdx.x & 63;
    const int blk  = blockIdx.x;
    const int tok0 = (blk * 4 + wave) * 4;

    if (threadIdx.x < NEXP) s_cnt[threadIdx.x] = 0;
    __syncthreads();

    // ---- phase 1: score (arithmetic identical to the verified version) ----
    const float4* x4 = reinterpret_cast<const float4*>(x);
    const float4* W4 = reinterpret_cast<const float4*>(W);

    float acc[4][NEXP];
#pragma unroll
    for (int t = 0; t < 4; ++t)
#pragma unroll
        for (int e = 0; e < NEXP; ++e) acc[t][e] = 0.f;

#pragma unroll 2
    for (int i = 0; i < 16; ++i) {
        const int d4 = lane + 64 * i;
        float4 xv[4];
#pragma unroll
        for (int t = 0; t < 4; ++t) xv[t] = x4[(size_t)(tok0 + t) * D4 + d4];
#pragma unroll
        for (int e = 0; e < NEXP; ++e) {
            const float4 w = W4[e * D4 + d4];
#pragma unroll
            for (int t = 0; t < 4; ++t) {
                acc[t][e] = fmaf(xv[t].x, w.x, acc[t][e]);
                acc[t][e] = fmaf(xv[t].y, w.y, acc[t][e]);
                acc[t][e] = fmaf(xv[t].z, w.z, acc[t][e]);
                acc[t][e] = fmaf(xv[t].w, w.w, acc[t][e]);
            }
        }
    }

#pragma unroll
    for (int t = 0; t < 4; ++t)
#pragma unroll
        for (int e = 0; e < NEXP; ++e) {
            float v = acc[t][e];
#pragma unroll
            for (int off = 32; off >= 1; off >>= 1) v += __shfl_xor(v, off);
            acc[t][e] = v;
        }

    // Top-2 + softmax; redundant on all lanes, lane t publishes token t to LDS.
#pragma unroll
    for (int t = 0; t < 4; ++t) {
        int i0 = 0;
        float m0 = acc[t][0];
#pragma unroll
        for (int e = 1; e < NEXP; ++e)
            if (acc[t][e] > m0) { m0 = acc[t][e]; i0 = e; }  // strict > keeps lowest idx
        int i1 = -1;
        float m1 = -INFINITY;
#pragma unroll
        for (int e = 0; e < NEXP; ++e)
            if (e != i0 && acc[t][e] > m1) { m1 = acc[t][e]; i1 = e; }
        const float z = __expf(m1 - m0);   // <= 1
        const float inv = 1.0f / (1.0f + z);
        if (lane == t) {
            const int ls = (wave * 4 + t) * 2;   // local slot in this block's chunk
            s_eid[ls]      = i0;
            s_eid[ls + 1]  = i1;
            s_prob[ls]     = inv;
            s_prob[ls + 1] = z * inv;
            atomicAdd(&s_cnt[i0], 1);
            atomicAdd(&s_cnt[i1], 1);
        }
    }
    __syncthreads();
    if (threadIdx.x < NEXP) hist[blk * NEXP + threadIdx.x] = s_cnt[threadIdx.x];

    // ---- grid barrier 1 (arrive) ----
    __syncthreads();   // hist stores drained before the fence
    if (threadIdx.x == 0) { __threadfence(); atomicAdd(&bar[0], 1); }

    // ---- block 0: exclusive scan of 512 chunks x 8 experts -> bases ----
    if (blk == 0) {
        if (threadIdx.x == 0) {
            while (__hip_atomic_load(&bar[0], __ATOMIC_ACQUIRE,
                                     __HIP_MEMORY_SCOPE_AGENT) < NBLK)
                __builtin_amdgcn_s_sleep(2);
        }
        __syncthreads();
        if (threadIdx.x < 64) {
            int v[NEXP][8];
#pragma unroll
            for (int q = 0; q < NEXP; ++q)
#pragma unroll
                for (int r = 0; r < 8; ++r)
                    v[q][r] = hist[(r * 64 + lane) * NEXP + q];
            int base = 0;
#pragma unroll
            for (int q = 0; q < NEXP; ++q) {
                int run = 0;
#pragma unroll
                for (int r = 0; r < 8; ++r) {
                    int incl = v[q][r];
#pragma unroll
                    for (int off = 1; off <= 32; off <<= 1) {
                        const int n = __shfl_up(incl, off);
                        if (lane >= off) incl += n;
                    }
                    hist[(r * 64 + lane) * NEXP + q] = base + run + incl - v[q][r];
                    run += __shfl(incl, 63);   // uniform
                }
                if (lane == 0) out[OUT_CNT + q] = (float)run;
                base += run;
            }
        }
    }

    // ---- grid barrier 2 (arrive + wait) ----
    __syncthreads();
    if (threadIdx.x == 0) {
        __threadfence();
        atomicAdd(&bar[32], 1);    // separate cache line from bar[0]
        while (__hip_atomic_load(&bar[32], __ATOMIC_ACQUIRE,
                                 __HIP_MEMORY_SCOPE_AGENT) < NBLK)
            __builtin_amdgcn_s_sleep(2);
    }
    __syncthreads();

    // ---- phase 3: rank own chunk, emit dstpos / scatter_indices / scores ----
    if (threadIdx.x < 64) {
        const int e = (lane < CH) ? s_eid[lane] : -1;
        const unsigned long long lt = (1ull << lane) - 1ull;
        int rank = 0;
#pragma unroll
        for (int q = 0; q < NEXP; ++q) {
            const unsigned long long m = __ballot(e == q);
            if (e == q) rank = __popcll(m & lt);
        }
        if (lane < CH) {
            const int p = hist[blk * NEXP + e] + rank;
            const int s = blk * CH + lane;          // global slot id
            dstpos[s] = p;
            out[OUT_SCAT + p]  = (float)(s >> 1);   // token id
            out[OUT_SCORE + p] = s_prob[lane];
        }
    }
}

// ---------------------------------------------------------------------------
// Kernel 2: gather. One block per token, 8192 blocks -> up to 8 blocks/CU
// (32 waves/CU) of outstanding loads+stores. REGULAR stores (A/B vs the
// nontemporal path: the 6.4 TB/s fill kernel uses regular stores).
// ---------------------------------------------------------------------------
__global__ __launch_bounds__(TPB) void k_gather(const float* __restrict__ x,
                                                const int* __restrict__ dstpos,
                                                float* __restrict__ out)
{
    const int t = blockIdx.x;
    const int p0 = dstpos[t * 2];
    const int p1 = dstpos[t * 2 + 1];
    const vfloat4* src = reinterpret_cast<const vfloat4*>(x) + (size_t)t * D4;
    vfloat4* o4 = reinterpret_cast<vfloat4*>(out);
    vfloat4* d0 = o4 + (size_t)p0 * D4;
    vfloat4* d1 = o4 + (size_t)p1 * D4;
#pragma unroll
    for (int i = 0; i < 4; ++i) {
        const int idx = threadIdx.x + TPB * i;
        const vfloat4 v = src[idx];
        d0[idx] = v;
        d1[idx] = v;
    }
}

extern "C" void kernel_launch(void* const* d_in, const int* in_sizes, int n_in,
                              void* d_out, int out_size, void* d_ws, size_t ws_size,
                              hipStream_t stream)
{
    const float* x = (const float*)d_in[0];
    const float* W = (const float*)d_in[1];
    float* out = (float*)d_out;

    // Workspace: hist[512*8] int at +0 | bar counters at +64KB | dstpos at +128KB
    int* hist   = (int*)d_ws;
    int* bar    = (int*)((char*)d_ws + 64 * 1024);
    int* dstpos = (int*)((char*)d_ws + 128 * 1024);

    hipMemsetAsync(bar, 0, 256, stream);   // reset both barrier counters (capture-safe)
    k_route<<<NBLK, TPB, 0, stream>>>(x, W, hist, bar, dstpos, out);
    k_gather<<<TOKENS, TPB, 0, stream>>>(x, dstpos, out);
}